// Round 18
// baseline (833.882 us; speedup 1.0000x reference)
//
#include <hip/hip_runtime.h>

#define DIM   1024
#define HEADS 16
#define HD    64
#define BB    2
#define SS    2048
#define LLL   2048
#define LOG2E 1.4426950408889634f

typedef __bf16 bf16x8 __attribute__((ext_vector_type(8)));
typedef __bf16 bf16x4v __attribute__((ext_vector_type(4)));
typedef float  f32x4  __attribute__((ext_vector_type(4)));
typedef short  s16x4  __attribute__((ext_vector_type(4)));
typedef unsigned short u16;

static __device__ __forceinline__ u16 f2b(float x) {
  unsigned u = __float_as_uint(x);
  u += 0x7fffu + ((u >> 16) & 1u);
  return (u16)(u >> 16);
}
static __device__ __forceinline__ float b2f(u16 u) {
  return __uint_as_float(((unsigned)u) << 16);
}
static __device__ __forceinline__ f32x4 mfma32(bf16x8 a, bf16x8 b, f32x4 c) {
  return __builtin_amdgcn_mfma_f32_16x16x32_bf16(a, b, c, 0, 0, 0);
}

// async global->LDS, 16B/lane. LDS base must be WAVE-UNIFORM (HW adds lane*16).
static __device__ __forceinline__ void gload_lds16(const void* g, void* lds_uniform_base) {
#if __has_builtin(__builtin_amdgcn_global_load_lds)
  __builtin_amdgcn_global_load_lds(
      (const __attribute__((address_space(1))) unsigned int*)g,
      (__attribute__((address_space(3))) unsigned int*)lds_uniform_base, 16, 0, 0);
#else
  const int l = threadIdx.x & 63;
  ((uint4*)lds_uniform_base)[l] = ((const uint4*)g)[0];
#endif
}

// ---------------- prep: fused f32->bf16 convert (query/Wq/Wo) + mask bit-pack ----------------
__global__ void prep(const float* __restrict__ a, const float* __restrict__ b,
                     const float* __restrict__ c, u16* __restrict__ da,
                     u16* __restrict__ db_, u16* __restrict__ dc,
                     const int* __restrict__ mask, unsigned* __restrict__ mbits,
                     int na4, int nb4, int ncvt) {
  int i = blockIdx.x * blockDim.x + threadIdx.x;
  if (i < ncvt) {
    const float* s; u16* d; int j = i;
    if (j < na4) { s = a; d = da; }
    else if ((j -= na4) < nb4) { s = b; d = db_; }
    else { j -= nb4; s = c; d = dc; }
    float4 f = ((const float4*)s)[j];
    ushort4 o;
    o.x = f2b(f.x); o.y = f2b(f.y); o.z = f2b(f.z); o.w = f2b(f.w);
    ((ushort4*)d)[j] = o;
  } else {
    int j = i - ncvt;  // over S*L/32
    const int* src = mask + (size_t)j * 32;
    unsigned bm = 0;
#pragma unroll
    for (int jj = 0; jj < 8; ++jj) {
      int4 m = ((const int4*)src)[jj];
      bm |= (m.x != 0 ? 1u : 0u) << (jj * 4 + 0);
      bm |= (m.y != 0 ? 1u : 0u) << (jj * 4 + 1);
      bm |= (m.z != 0 ? 1u : 0u) << (jj * 4 + 2);
      bm |= (m.w != 0 ? 1u : 0u) << (jj * 4 + 3);
    }
    mbits[j] = bm;
  }
}

// ---------------- K (f32) -> fragment-packed bf16 tiles, PRESCALED by 0.125*log2(e) ----------------
__global__ __launch_bounds__(256) void pack_k(const float* __restrict__ k0,
                                              const float* __restrict__ k1,
                                              u16* __restrict__ Kfrag) {
  const float SCK = 0.125f * LOG2E;
  const int w = threadIdx.x >> 6, l = threadIdx.x & 63, g = l >> 4, li = l & 15;
  const int lt = blockIdx.x * 4 + w, h = blockIdx.y, z = blockIdx.z;
  const int lay = z >> 1, b = z & 1;
  const float* src = (lay ? k1 : k0) + (size_t)b * LLL * DIM;
  u16* dst = Kfrag + ((((size_t)z * HEADS + h) * 32 + lt) * 8) * 512;
#pragma unroll
  for (int c = 0; c < 8; ++c) {
    int mt = c >> 1, kk = c & 1;
    const float* p = &src[(size_t)(lt * 64 + mt * 16 + li) * DIM + h * 64 + kk * 32 + g * 8];
    float4 f0 = *(const float4*)p;
    float4 f1 = *(const float4*)(p + 4);
    u16 u[8] = {f2b(f0.x * SCK), f2b(f0.y * SCK), f2b(f0.z * SCK), f2b(f0.w * SCK),
                f2b(f1.x * SCK), f2b(f1.y * SCK), f2b(f1.z * SCK), f2b(f1.w * SCK)};
    *(uint4*)&dst[c * 512 + l * 8] = *(uint4*)u;
  }
}

// ---------------- V (f32) -> K=32-PV fragment layout ----------------
__global__ __launch_bounds__(256) void pack_v(const float* __restrict__ v0,
                                              const float* __restrict__ v1,
                                              u16* __restrict__ Vfrag) {
  __shared__ u16 T[64][72];  // T[l][d]
  const int lt = blockIdx.x, h = blockIdx.y, z = blockIdx.z;
  const int lay = z >> 1, b = z & 1;
  const float* v = (lay ? v1 : v0) + (size_t)b * LLL * DIM;
  const int t = threadIdx.x;
  {
    int r = t >> 2, c16 = (t & 3) * 16;
    const float* src = &v[(size_t)(lt * 64 + r) * DIM + h * 64 + c16];
#pragma unroll
    for (int i = 0; i < 4; ++i) {
      float4 f = *(const float4*)&src[i * 4];
      T[r][c16 + i * 4 + 0] = f2b(f.x);
      T[r][c16 + i * 4 + 1] = f2b(f.y);
      T[r][c16 + i * 4 + 2] = f2b(f.z);
      T[r][c16 + i * 4 + 3] = f2b(f.w);
    }
  }
  __syncthreads();
  u16* dst = Vfrag + ((((size_t)z * HEADS + h) * 32 + lt) * 8) * 512;
  {
    int lane = t & 63, g = lane >> 4, li = lane & 15;
#pragma unroll
    for (int cc = 0; cc < 2; ++cc) {
      int c = (t >> 6) + cc * 4;           // 0..7
      int pair = c >> 2, dt = c & 3;
      u16 u[8];
#pragma unroll
      for (int j = 0; j < 4; ++j) u[j]     = T[pair * 32 + 4 * g + j][dt * 16 + li];
#pragma unroll
      for (int j = 0; j < 4; ++j) u[4 + j] = T[pair * 32 + 16 + 4 * g + j][dt * 16 + li];
      *(uint4*)&dst[c * 512 + lane * 8] = *(uint4*)u;
    }
  }
}

// ---------------- bf16 NT GEMM, 128x64 tile, double-buffered global_load_lds staging ----------------
template<int MODE>
__global__ __launch_bounds__(256) void gemm_nt(const u16* __restrict__ A,
                                               const u16* __restrict__ Bt,
                                               const float* __restrict__ bias,
                                               void* __restrict__ Cv,
                                               int M, int N, int K) {
  __shared__ u16 As[2][128][64];
  __shared__ u16 Bs[2][64][64];
  const int t = threadIdx.x;
  const int w = t >> 6, l = t & 63, g = l >> 4, li = l & 15;
  const int m0 = blockIdx.y * 128, n0 = blockIdx.x * 64;
  const int slotL = w * 64 + l;
  const int rA = slotL >> 3, cA = ((slotL & 7) * 8) ^ ((rA & 7) * 8);

  auto stageAB = [&](int buf, int kt) {
#pragma unroll
    for (int s = 0; s < 4; ++s) {
      int r = rA + s * 32;
      gload_lds16(&A[(size_t)(m0 + r) * K + kt + cA], &As[buf][0][0] + (s * 256 + w * 64) * 8);
    }
#pragma unroll
    for (int s = 0; s < 2; ++s) {
      int r = rA + s * 32;
      gload_lds16(&Bt[(size_t)(n0 + r) * K + kt + cA], &Bs[buf][0][0] + (s * 256 + w * 64) * 8);
    }
  };

  f32x4 acc[2][4] = {};
  stageAB(0, 0);
  __syncthreads();
  int cur = 0;
  for (int kt = 0; kt < K; kt += 64) {
    if (kt + 64 < K) stageAB(cur ^ 1, kt + 64);
#pragma unroll
    for (int kk = 0; kk < 2; ++kk) {
      bf16x8 a[2], bfr[4];
#pragma unroll
      for (int mi = 0; mi < 2; ++mi) {
        int ra = w * 32 + mi * 16 + li;
        a[mi] = *(const bf16x8*)&As[cur][ra][(kk * 32 + g * 8) ^ ((ra & 7) << 3)];
      }
#pragma unroll
      for (int ni = 0; ni < 4; ++ni) {
        int rb = ni * 16 + li;
        bfr[ni] = *(const bf16x8*)&Bs[cur][rb][(kk * 32 + g * 8) ^ ((rb & 7) << 3)];
      }
#pragma unroll
      for (int mi = 0; mi < 2; ++mi)
#pragma unroll
        for (int ni = 0; ni < 4; ++ni)
          acc[mi][ni] = mfma32(a[mi], bfr[ni], acc[mi][ni]);
    }
    __syncthreads();
    cur ^= 1;
  }
#pragma unroll
  for (int mi = 0; mi < 2; ++mi)
#pragma unroll
    for (int ni = 0; ni < 4; ++ni)
#pragma unroll
      for (int v = 0; v < 4; ++v) {
        int rr = m0 + w * 32 + mi * 16 + g * 4 + v;
        int cc = n0 + ni * 16 + li;
        float val = acc[mi][ni][v] + bias[cc];
        if (MODE == 1) {
          ((float*)Cv)[(size_t)rr * N + cc] = val;
        } else {
          // Qfrag[b][h][qt][c=n*2+kk][lane(gp,liq)][8]
          int b = rr >> 11, q = rr & 2047;
          int qt = q >> 5, n = (q >> 4) & 1, liq = q & 15;
          int h = (cc >> 6) & 15, kk2 = (cc >> 5) & 1, gp = (cc >> 3) & 3, j = cc & 7;
          size_t base = ((((size_t)b * HEADS + h) * 64 + qt) * 4 + n * 2 + kk2) * 512;
          ((u16*)Cv)[base + (size_t)(gp * 16 + liq) * 8 + j] = f2b(val);
        }
      }
}

// ---------------- attn_pv: 16-wave blocks, L-split into 2 groups of 8 waves ----------------
// group g2 covers lt in [g2*16, g2*16+16); partials combined via SoA LDS exchange.
// db layout: [z*HEADS+h][q] = dinv
template<int MASKED>
static __device__ __forceinline__ void attn_pv_body(int z, int h, int qt, int g2, int wg, int l,
                                                    const u16* __restrict__ Qfrag,
                                                    const u16* __restrict__ Kfrag,
                                                    const u16* __restrict__ Vfrag,
                                                    const unsigned* __restrict__ mbits,
                                                    u16* __restrict__ out01,
                                                    float* __restrict__ db,
                                                    u16* __restrict__ KVall) {
  const int g = l >> 4, li = l & 15;
  const int b = z & 1;
  const u16* kfh = Kfrag + (size_t)(z * HEADS + h) * (32 * 8 * 512);
  const u16* vfh = Vfrag + (size_t)(z * HEADS + h) * (32 * 8 * 512);
  const u16* qfh = Qfrag + (((size_t)(b * HEADS + h) * 64 + qt) * 4) * 512;
  u16* KV = KVall + (size_t)g2 * 16384;  // group-private 32 KB double buffer

  bf16x8 qf[2][2];
#pragma unroll
  for (int n = 0; n < 2; ++n)
#pragma unroll
    for (int kk = 0; kk < 2; ++kk)
      qf[n][kk] = *(const bf16x8*)&qfh[(n * 2 + kk) * 512 + l * 8];

  const unsigned* mrow0 = MASKED ? mbits + (size_t)(qt * 32 + li) * (LLL / 32) : nullptr;
  const unsigned* mrow1 = MASKED ? mrow0 + 16 * (LLL / 32) : nullptr;
  const int shb = 4 * g;
  bf16x8 ones8;
#pragma unroll
  for (int j = 0; j < 8; ++j) ones8[j] = __builtin_bit_cast(__bf16, (u16)0x3F80);

  auto stage = [&](int buf, int lt) {
    const u16* kfl = kfh + (size_t)lt * 4096;
    const u16* vfl = vfh + (size_t)lt * 4096;
#pragma unroll
    for (int i2 = 0; i2 < 2; ++i2) {
      int f = wg * 2 + i2;
      const u16* gsrc = (f < 8 ? kfl + f * 512 : vfl + (f - 8) * 512) + l * 8;
      gload_lds16(gsrc, (char*)KV + buf * 16384 + f * 1024);
    }
  };

  f32x4 dacc[2] = {};     // denominator per n-half (matrix pipe, A = ones)
  f32x4 oacc[4][2] = {};  // [dt][n], unnormalized

  const int lt0 = g2 * 16;
  stage(0, lt0);
  __syncthreads();
  int cur = 0;
  for (int it = 0; it < 16; ++it) {
    const int lt = lt0 + it;
    if (it + 1 < 16) stage(cur ^ 1, lt + 1);  // prefetch flies under compute
    unsigned mw[2][2];
    if (MASKED) {
      mw[0][0] = mrow0[lt * 2]; mw[0][1] = mrow0[lt * 2 + 1];
      mw[1][0] = mrow1[lt * 2]; mw[1][1] = mrow1[lt * 2 + 1];
    }
    const u16* Ks = KV + cur * 8192;
    const u16* Vs = Ks + 4096;

    auto qk = [&](f32x4 (&s)[2], int mt) {
      bf16x8 k0 = *(const bf16x8*)&Ks[(mt * 2 + 0) * 512 + l * 8];
      bf16x8 k1 = *(const bf16x8*)&Ks[(mt * 2 + 1) * 512 + l * 8];
      f32x4 zz = {};
      __builtin_amdgcn_s_setprio(1);
      s[0] = mfma32(k0, qf[0][0], zz);
      s[0] = mfma32(k1, qf[0][1], s[0]);
      s[1] = mfma32(k0, qf[1][0], zz);
      s[1] = mfma32(k1, qf[1][1], s[1]);
      __builtin_amdgcn_s_setprio(0);
    };
    auto sm = [&](f32x4 (&s)[2], int mt, s16x4 (&wpk)[2]) {
#pragma unroll
      for (int n = 0; n < 2; ++n) {
        unsigned mm = MASKED ? (mw[n][mt >> 1] >> ((mt & 1) * 16 + shb)) : 0u;
        f32x4 ev;
#pragma unroll
        for (int v = 0; v < 4; ++v) {
          float e = __builtin_amdgcn_exp2f(s[n][v]);    // K prescaled: zero prep
          if (MASKED) {
            int spread = ((int)(mm << (31 - v))) >> 31; // all-ones if keep
            e = __uint_as_float(__float_as_uint(e) & (unsigned)spread);
          }
          ev[v] = e;
        }
        bf16x4v wb = __builtin_convertvector(ev, bf16x4v);
        wpk[n] = __builtin_bit_cast(s16x4, wb);
      }
    };
    auto pv_pair = [&](s16x4 (&w0)[2], s16x4 (&w1)[2], int pair) {
      bf16x8 w8[2];
#pragma unroll
      for (int n = 0; n < 2; ++n) {
        bf16x4v a0 = __builtin_bit_cast(bf16x4v, w0[n]);
        bf16x4v a1 = __builtin_bit_cast(bf16x4v, w1[n]);
        w8[n] = __builtin_shufflevector(a0, a1, 0, 1, 2, 3, 4, 5, 6, 7);
      }
      __builtin_amdgcn_s_setprio(1);
      dacc[0] = mfma32(ones8, w8[0], dacc[0]);
      dacc[1] = mfma32(ones8, w8[1], dacc[1]);
#pragma unroll
      for (int dt = 0; dt < 4; ++dt) {
        bf16x8 vf = *(const bf16x8*)&Vs[(pair * 4 + dt) * 512 + l * 8];
#pragma unroll
        for (int n = 0; n < 2; ++n)
          oacc[dt][n] = mfma32(vf, w8[n], oacc[dt][n]);
      }
      __builtin_amdgcn_s_setprio(0);
    };

    f32x4 sA[2], sB[2];
    s16x4 wA[2], wB[2];
    qk(sA, 0); qk(sB, 1);
    sm(sA, 0, wA);
    qk(sA, 2);            // next pair's first QK overlaps sm/PV of pair 0
    sm(sB, 1, wB);
    pv_pair(wA, wB, 0);
    qk(sB, 3);
    sm(sA, 2, wA);
    sm(sB, 3, wB);
    pv_pair(wA, wB, 1);
    __syncthreads();
    cur ^= 1;
  }

  // ---- cross-group partial combine (SoA, conflict-free f32x4 slots) ----
  float* X = (float*)KVall;  // 64 KB scratch, loop buffers dead now
  const int slot = (wg * 64 + l) * 4;
  // round 1: dacc[0], dacc[1], oacc[0][0], oacc[0][1], oacc[1][0], oacc[1][1]
  if (g2 == 1) {
    *(f32x4*)&X[0 * 2048 + slot] = dacc[0];
    *(f32x4*)&X[1 * 2048 + slot] = dacc[1];
    *(f32x4*)&X[2 * 2048 + slot] = oacc[0][0];
    *(f32x4*)&X[3 * 2048 + slot] = oacc[0][1];
    *(f32x4*)&X[4 * 2048 + slot] = oacc[1][0];
    *(f32x4*)&X[5 * 2048 + slot] = oacc[1][1];
  }
  __syncthreads();
  if (g2 == 0) {
    dacc[0]    += *(const f32x4*)&X[0 * 2048 + slot];
    dacc[1]    += *(const f32x4*)&X[1 * 2048 + slot];
    oacc[0][0] += *(const f32x4*)&X[2 * 2048 + slot];
    oacc[0][1] += *(const f32x4*)&X[3 * 2048 + slot];
    oacc[1][0] += *(const f32x4*)&X[4 * 2048 + slot];
    oacc[1][1] += *(const f32x4*)&X[5 * 2048 + slot];
  }
  __syncthreads();
  // round 2: oacc[2][*], oacc[3][*]
  if (g2 == 1) {
    *(f32x4*)&X[0 * 2048 + slot] = oacc[2][0];
    *(f32x4*)&X[1 * 2048 + slot] = oacc[2][1];
    *(f32x4*)&X[2 * 2048 + slot] = oacc[3][0];
    *(f32x4*)&X[3 * 2048 + slot] = oacc[3][1];
  }
  __syncthreads();
  if (g2 == 0) {
    oacc[2][0] += *(const f32x4*)&X[0 * 2048 + slot];
    oacc[2][1] += *(const f32x4*)&X[1 * 2048 + slot];
    oacc[3][0] += *(const f32x4*)&X[2 * 2048 + slot];
    oacc[3][1] += *(const f32x4*)&X[3 * 2048 + slot];

    float dinv[2];
    dinv[0] = 1.0f / dacc[0][0];
    dinv[1] = 1.0f / dacc[1][0];
    if (l < 16) {
      db[(size_t)(z * HEADS + h) * SS + qt * 32 + li]      = dinv[0];
      db[(size_t)(z * HEADS + h) * SS + qt * 32 + 16 + li] = dinv[1];
    }
    u16* ob = out01 + (size_t)z * SS * DIM;
#pragma unroll
    for (int dt = 0; dt < 4; ++dt)
#pragma unroll
      for (int n = 0; n < 2; ++n) {
        f32x4 o = oacc[dt][n] * dinv[n];
        ushort4 us;
        us.x = f2b(o[0]); us.y = f2b(o[1]); us.z = f2b(o[2]); us.w = f2b(o[3]);
        *(ushort4*)&ob[((size_t)(qt * 32 + n * 16 + li)) * DIM + h * HD + dt * 16 + 4 * g] = us;
      }
  }
}

__global__ __launch_bounds__(1024, 8) void attn_pv(const u16* __restrict__ Qfrag,
                                                   const u16* __restrict__ Kfrag,
                                                   const u16* __restrict__ Vfrag,
                                                   const unsigned* __restrict__ mbits,
                                                   u16* __restrict__ out01,
                                                   float* __restrict__ db) {
  __shared__ u16 KV[2][2][8192];  // [group][buf]: 64 KB total
  // z-balanced XCD map (512 blocks): each XCD gets zh spanning all z
  const int flat = blockIdx.x;
  const int xcd = flat & 7, i = flat >> 3;     // i in [0,64)
  const int k = i >> 3, qg = i & 7;            // k in [0,8)
  const int zh = xcd + 8 * k;                  // [0,64)
  const int z = zh >> 4, h = zh & 15;
  const int w = threadIdx.x >> 6, l = threadIdx.x & 63;
  const int g2 = w >> 3, wg = w & 7;
  const int qt = qg * 8 + wg;                  // [0,64)
  if (z < 2) attn_pv_body<1>(z, h, qt, g2, wg, l, Qfrag, Kfrag, Vfrag, mbits, out01, db, &KV[0][0][0]);
  else       attn_pv_body<0>(z, h, qt, g2, wg, l, Qfrag, Kfrag, Vfrag, mbits, out01, db, &KV[0][0][0]);
}

// ---------------- amean: 32 q-rows/wave, LDS-staged K; mask hoisted out of the h-loop ----------------
template<int MASKED>
static __device__ __forceinline__ void amean_body(int z, int qt, int lt, int w, int l,
                                                  const u16* __restrict__ Qfrag,
                                                  const u16* __restrict__ Kfrag,
                                                  const unsigned* __restrict__ mbits,
                                                  const float* __restrict__ db,
                                                  float* __restrict__ aout,
                                                  u16* __restrict__ KS) {
  const int g = l >> 4, li = l & 15;
  const int b = z & 1;

  const u16* qf_base = Qfrag + (((size_t)(b * HEADS) * 64 + qt) * 4) * 512 + l * 8;
  const float* dbb = db + (size_t)(z * HEADS) * SS + qt * 32 + li;

  auto stageK = [&](int buf, int h) {
    const u16* kfh = Kfrag + ((((size_t)(z * HEADS + h)) * 32 + lt) * 8) * 512;
#pragma unroll
    for (int i2 = 0; i2 < 2; ++i2) {
      int f = w * 2 + i2;
      gload_lds16(kfh + f * 512 + l * 8, (char*)KS + buf * 8192 + f * 1024);
    }
  };

  f32x4 asum[4][2] = {};
  stageK(0, 0);
  __syncthreads();
#pragma unroll 2
  for (int h = 0; h < HEADS; ++h) {
    if (h + 1 < HEADS) stageK((h + 1) & 1, h + 1);   // prefetch under compute
    float dv[2];
    dv[0] = dbb[(size_t)h * SS];                     // dinv, precomputed (mask-correct)
    dv[1] = dbb[(size_t)h * SS + 16];
    bf16x8 qf[2][2];
#pragma unroll
    for (int n = 0; n < 2; ++n)
#pragma unroll
      for (int kk = 0; kk < 2; ++kk)
        qf[n][kk] = *(const bf16x8*)&qf_base[(size_t)h * (64 * 4 * 512) + (n * 2 + kk) * 512];
    const u16* Ks = KS + (h & 1) * 4096;
#pragma unroll
    for (int mt = 0; mt < 4; ++mt) {
      bf16x8 k0 = *(const bf16x8*)&Ks[(mt * 2 + 0) * 512 + l * 8];
      bf16x8 k1 = *(const bf16x8*)&Ks[(mt * 2 + 1) * 512 + l * 8];
#pragma unroll
      for (int n = 0; n < 2; ++n) {
        f32x4 s = {};
        s = mfma32(k0, qf[n][0], s);
        s = mfma32(k1, qf[n][1], s);
#pragma unroll
        for (int v = 0; v < 4; ++v)
          asum[mt][n][v] = __builtin_fmaf(__builtin_amdgcn_exp2f(s[v]), dv[n], asum[mt][n][v]);
      }
    }
    __syncthreads();  // waves done reading Ks[h&1]; h+1 loads drained
  }
  // final mask (once per output element) + scale + store
  float* ab = aout + (size_t)z * SS * LLL;
#pragma unroll
  for (int mt = 0; mt < 4; ++mt)
#pragma unroll
    for (int n = 0; n < 2; ++n) {
      f32x4 o = asum[mt][n] * 0.0625f;
      if (MASKED) {
        const unsigned* mrow = mbits + (size_t)(qt * 32 + n * 16 + li) * (LLL / 32) + lt * 2;
        unsigned mm = mrow[mt >> 1] >> ((mt & 1) * 16 + 4 * g);
#pragma unroll
        for (int v = 0; v < 4; ++v) {
          int spread = ((int)(mm << (31 - v))) >> 31;  // all-ones if keep
          o[v] = __uint_as_float(__float_as_uint(o[v]) & (unsigned)spread);
        }
      }
      f32x4* dst = (f32x4*)&ab[(size_t)(qt * 32 + n * 16 + li) * LLL + lt * 64 + mt * 16 + 4 * g];
      __builtin_nontemporal_store(o, dst);
    }
}

__global__ __launch_bounds__(256, 4) void amean(const u16* __restrict__ Qfrag,
                                                const u16* __restrict__ Kfrag,
                                                const unsigned* __restrict__ mbits,
                                                const float* __restrict__ db,
                                                float* __restrict__ aout) {
  __shared__ u16 KS[2][4096];  // 16 KB double-buffered K tile
  // z-balanced XCD map over (z,lt) groups (2048 blocks)
  const int flat = blockIdx.x;
  const int xcd = flat & 7, i = flat >> 3;     // i in [0,256)
  const int k = i >> 4, qg = i & 15;           // k in [0,16)
  const int zlt = xcd + 8 * k;                 // [0,128)
  const int z = zlt >> 5, lt = zlt & 31;
  const int w = threadIdx.x >> 6, l = threadIdx.x & 63;
  const int qt = qg * 4 + w;                   // [0,64)
  if (z < 2) amean_body<1>(z, qt, lt, w, l, Qfrag, Kfrag, mbits, db, aout, &KS[0][0]);
  else       amean_body<0>(z, qt, lt, w, l, Qfrag, Kfrag, mbits, db, aout, &KS[0][0]);
}

// ---------------- gated merge ----------------
__global__ void merge_kernel(const u16* __restrict__ o01,
                             const float* __restrict__ gate,
                             u16* __restrict__ merged) {
  int i = blockIdx.x * blockDim.x + threadIdx.x;
  float gv = gate[0];
  float g = 1.0f / (1.0f + __builtin_amdgcn_exp2f(-gv * LOG2E));
  const size_t n = (size_t)BB * SS * DIM;
  ushort4 a = ((const ushort4*)o01)[i];
  ushort4 c = ((const ushort4*)(o01 + n))[i];
  ushort4 o;
  o.x = f2b(g * b2f(a.x) + (1.f - g) * b2f(c.x));
  o.y = f2b(g * b2f(a.y) + (1.f - g) * b2f(c.y));
  o.z = f2b(g * b2f(a.z) + (1.f - g) * b2f(c.z));
  o.w = f2b(g * b2f(a.w) + (1.f - g) * b2f(c.w));
  ((ushort4*)merged)[i] = o;
}

extern "C" void kernel_launch(void* const* d_in, const int* in_sizes, int n_in,
                              void* d_out, int out_size, void* d_ws, size_t ws_size,
                              hipStream_t stream) {
  const float* query = (const float*)d_in[0];
  const float* k0f   = (const float*)d_in[1];
  const float* v0f   = (const float*)d_in[2];
  const float* k1f   = (const float*)d_in[3];
  const float* v1f   = (const float*)d_in[4];
  const int*   mask  = (const int*)d_in[5];
  const float* Wqf   = (const float*)d_in[6];
  const float* bq    = (const float*)d_in[7];
  const float* Wof   = (const float*)d_in[8];
  const float* bo    = (const float*)d_in[9];
  const float* gate  = (const float*)d_in[10];
  float* out = (float*)d_out;

  const size_t nQ = (size_t)BB * SS * DIM;
  const size_t nW = (size_t)DIM * DIM;

  char* ws = (char*)d_ws;
  size_t off = 0;
  auto alloc = [&](size_t bytes) -> char* {
    char* p = ws + off;
    off += (bytes + 255) & ~(size_t)255;
    return p;
  };
  u16*      queryb  = (u16*)alloc(nQ * 2);             // reused as mergedb later
  u16*      wqb     = (u16*)alloc(nW * 2);
  u16*      wob     = (u16*)alloc(nW * 2);
  u16*      Qfrag   = (u16*)alloc(nQ * 2);             // [b][h][qt][c][lane][8]
  u16*      Kfrag   = (u16*)alloc((size_t)2 * nQ * 2); // [z][h][lt][c][lane][8] (prescaled)
  u16*      Vfrag   = (u16*)alloc((size_t)2 * nQ * 2); // K=32-PV layout
  unsigned* mbits   = (unsigned*)alloc((size_t)SS * (LLL / 32) * 4);
  float*    db      = (float*)alloc((size_t)4 * HEADS * SS * 4);  // dinv per [z][h][q]
  u16*      out01   = (u16*)alloc((size_t)2 * nQ * 2);
  u16*      mergedb = queryb;  // queryb dead after q-proj gemm

  {
    int na4 = (int)(nQ / 4), nb4 = (int)(nW / 4);
    int ncvt = na4 + 2 * nb4;
    int nmask = SS * (LLL / 32);
    prep<<<dim3((ncvt + nmask) / 256), dim3(256), 0, stream>>>(
        query, Wqf, Wof, queryb, wqb, wob, mask, mbits, na4, nb4, ncvt);
  }

  pack_k<<<dim3(LLL / 64 / 4, HEADS, 4), dim3(256), 0, stream>>>(k0f, k1f, Kfrag);
  pack_v<<<dim3(LLL / 64, HEADS, 4), dim3(256), 0, stream>>>(v0f, v1f, Vfrag);

  // q projection straight into fragment layout (128x64 tiles, double-buffered)
  gemm_nt<2><<<dim3(DIM / 64, (BB * SS) / 128), dim3(256), 0, stream>>>(
      queryb, wqb, bq, (void*)Qfrag, BB * SS, DIM, DIM);

  // fused single-pass attention: 16-wave blocks, L-split groups, all-K=32 MFMA
  attn_pv<<<dim3(512), dim3(1024), 0, stream>>>(Qfrag, Kfrag, Vfrag, mbits, out01, db);

  // head-mean attention maps straight into d_out (4-wave shared K tiles, mask hoisted)
  amean<<<dim3(2048), dim3(256), 0, stream>>>(Qfrag, Kfrag, mbits, db, out + nQ);

  merge_kernel<<<dim3((int)(nQ / 4 / 256)), dim3(256), 0, stream>>>(out01, gate, mergedb);

  gemm_nt<1><<<dim3(DIM / 64, (BB * SS) / 128), dim3(256), 0, stream>>>(
      mergedb, wob, bo, (void*)out, BB * SS, DIM, DIM);
}

// Round 19
// 207.099 us; speedup vs baseline: 4.0265x; 4.0265x over previous
//
#include <hip/hip_runtime.h>

#define DIM   1024
#define HEADS 16
#define HD    64
#define BB    2
#define SS    2048
#define LLL   2048
#define LOG2E 1.4426950408889634f

typedef __bf16 bf16x8 __attribute__((ext_vector_type(8)));
typedef __bf16 bf16x4v __attribute__((ext_vector_type(4)));
typedef float  f32x4  __attribute__((ext_vector_type(4)));
typedef short  s16x4  __attribute__((ext_vector_type(4)));
typedef unsigned short u16;

static __device__ __forceinline__ u16 f2b(float x) {
  unsigned u = __float_as_uint(x);
  u += 0x7fffu + ((u >> 16) & 1u);
  return (u16)(u >> 16);
}
static __device__ __forceinline__ float b2f(u16 u) {
  return __uint_as_float(((unsigned)u) << 16);
}
static __device__ __forceinline__ f32x4 mfma32(bf16x8 a, bf16x8 b, f32x4 c) {
  return __builtin_amdgcn_mfma_f32_16x16x32_bf16(a, b, c, 0, 0, 0);
}

// async global->LDS, 16B/lane. LDS base must be WAVE-UNIFORM (HW adds lane*16).
static __device__ __forceinline__ void gload_lds16(const void* g, void* lds_uniform_base) {
#if __has_builtin(__builtin_amdgcn_global_load_lds)
  __builtin_amdgcn_global_load_lds(
      (const __attribute__((address_space(1))) unsigned int*)g,
      (__attribute__((address_space(3))) unsigned int*)lds_uniform_base, 16, 0, 0);
#else
  const int l = threadIdx.x & 63;
  ((uint4*)lds_uniform_base)[l] = ((const uint4*)g)[0];
#endif
}

// ---------------- prep: fused f32->bf16 convert (query/Wq/Wo) + mask bit-pack ----------------
__global__ void prep(const float* __restrict__ a, const float* __restrict__ b,
                     const float* __restrict__ c, u16* __restrict__ da,
                     u16* __restrict__ db_, u16* __restrict__ dc,
                     const int* __restrict__ mask, unsigned* __restrict__ mbits,
                     int na4, int nb4, int ncvt) {
  int i = blockIdx.x * blockDim.x + threadIdx.x;
  if (i < ncvt) {
    const float* s; u16* d; int j = i;
    if (j < na4) { s = a; d = da; }
    else if ((j -= na4) < nb4) { s = b; d = db_; }
    else { j -= nb4; s = c; d = dc; }
    float4 f = ((const float4*)s)[j];
    ushort4 o;
    o.x = f2b(f.x); o.y = f2b(f.y); o.z = f2b(f.z); o.w = f2b(f.w);
    ((ushort4*)d)[j] = o;
  } else {
    int j = i - ncvt;  // over S*L/32
    const int* src = mask + (size_t)j * 32;
    unsigned bm = 0;
#pragma unroll
    for (int jj = 0; jj < 8; ++jj) {
      int4 m = ((const int4*)src)[jj];
      bm |= (m.x != 0 ? 1u : 0u) << (jj * 4 + 0);
      bm |= (m.y != 0 ? 1u : 0u) << (jj * 4 + 1);
      bm |= (m.z != 0 ? 1u : 0u) << (jj * 4 + 2);
      bm |= (m.w != 0 ? 1u : 0u) << (jj * 4 + 3);
    }
    mbits[j] = bm;
  }
}

// ---------------- K (f32) -> fragment-packed bf16 tiles, PRESCALED by 0.125*log2(e) ----------------
__global__ __launch_bounds__(256) void pack_k(const float* __restrict__ k0,
                                              const float* __restrict__ k1,
                                              u16* __restrict__ Kfrag) {
  const float SCK = 0.125f * LOG2E;
  const int w = threadIdx.x >> 6, l = threadIdx.x & 63, g = l >> 4, li = l & 15;
  const int lt = blockIdx.x * 4 + w, h = blockIdx.y, z = blockIdx.z;
  const int lay = z >> 1, b = z & 1;
  const float* src = (lay ? k1 : k0) + (size_t)b * LLL * DIM;
  u16* dst = Kfrag + ((((size_t)z * HEADS + h) * 32 + lt) * 8) * 512;
#pragma unroll
  for (int c = 0; c < 8; ++c) {
    int mt = c >> 1, kk = c & 1;
    const float* p = &src[(size_t)(lt * 64 + mt * 16 + li) * DIM + h * 64 + kk * 32 + g * 8];
    float4 f0 = *(const float4*)p;
    float4 f1 = *(const float4*)(p + 4);
    u16 u[8] = {f2b(f0.x * SCK), f2b(f0.y * SCK), f2b(f0.z * SCK), f2b(f0.w * SCK),
                f2b(f1.x * SCK), f2b(f1.y * SCK), f2b(f1.z * SCK), f2b(f1.w * SCK)};
    *(uint4*)&dst[c * 512 + l * 8] = *(uint4*)u;
  }
}

// ---------------- V (f32) -> K=32-PV fragment layout ----------------
__global__ __launch_bounds__(256) void pack_v(const float* __restrict__ v0,
                                              const float* __restrict__ v1,
                                              u16* __restrict__ Vfrag) {
  __shared__ u16 T[64][72];  // T[l][d]
  const int lt = blockIdx.x, h = blockIdx.y, z = blockIdx.z;
  const int lay = z >> 1, b = z & 1;
  const float* v = (lay ? v1 : v0) + (size_t)b * LLL * DIM;
  const int t = threadIdx.x;
  {
    int r = t >> 2, c16 = (t & 3) * 16;
    const float* src = &v[(size_t)(lt * 64 + r) * DIM + h * 64 + c16];
#pragma unroll
    for (int i = 0; i < 4; ++i) {
      float4 f = *(const float4*)&src[i * 4];
      T[r][c16 + i * 4 + 0] = f2b(f.x);
      T[r][c16 + i * 4 + 1] = f2b(f.y);
      T[r][c16 + i * 4 + 2] = f2b(f.z);
      T[r][c16 + i * 4 + 3] = f2b(f.w);
    }
  }
  __syncthreads();
  u16* dst = Vfrag + ((((size_t)z * HEADS + h) * 32 + lt) * 8) * 512;
  {
    int lane = t & 63, g = lane >> 4, li = lane & 15;
#pragma unroll
    for (int cc = 0; cc < 2; ++cc) {
      int c = (t >> 6) + cc * 4;           // 0..7
      int pair = c >> 2, dt = c & 3;
      u16 u[8];
#pragma unroll
      for (int j = 0; j < 4; ++j) u[j]     = T[pair * 32 + 4 * g + j][dt * 16 + li];
#pragma unroll
      for (int j = 0; j < 4; ++j) u[4 + j] = T[pair * 32 + 16 + 4 * g + j][dt * 16 + li];
      *(uint4*)&dst[c * 512 + lane * 8] = *(uint4*)u;
    }
  }
}

// ---------------- bf16 NT GEMM, 128x64 tile, double-buffered global_load_lds staging ----------------
// 1-D grid, XCD-chunked: each XCD owns 4 consecutive m-panels x all 16 n-tiles
// so its L2 holds the 4 A-panels (4 MB) + whole B (2 MB).
template<int MODE>
__global__ __launch_bounds__(256) void gemm_nt(const u16* __restrict__ A,
                                               const u16* __restrict__ Bt,
                                               const float* __restrict__ bias,
                                               void* __restrict__ Cv,
                                               int M, int N, int K) {
  __shared__ u16 As[2][128][64];
  __shared__ u16 Bs[2][64][64];
  const int t = threadIdx.x;
  const int w = t >> 6, l = t & 63, g = l >> 4, li = l & 15;
  // XCD-chunked decomposition of the 512-block grid
  const int flat = blockIdx.x;
  const int xcd = flat & 7, i = flat >> 3;     // i in [0,64)
  const int mloc = i >> 4, nblk = i & 15;      // 4 m-panels x 16 n-tiles per XCD
  const int m0 = (xcd * 4 + mloc) * 128, n0 = nblk * 64;
  const int slotL = w * 64 + l;
  const int rA = slotL >> 3, cA = ((slotL & 7) * 8) ^ ((rA & 7) * 8);

  auto stageAB = [&](int buf, int kt) {
#pragma unroll
    for (int s = 0; s < 4; ++s) {
      int r = rA + s * 32;
      gload_lds16(&A[(size_t)(m0 + r) * K + kt + cA], &As[buf][0][0] + (s * 256 + w * 64) * 8);
    }
#pragma unroll
    for (int s = 0; s < 2; ++s) {
      int r = rA + s * 32;
      gload_lds16(&Bt[(size_t)(n0 + r) * K + kt + cA], &Bs[buf][0][0] + (s * 256 + w * 64) * 8);
    }
  };

  f32x4 acc[2][4] = {};
  stageAB(0, 0);
  __syncthreads();
  int cur = 0;
  for (int kt = 0; kt < K; kt += 64) {
    if (kt + 64 < K) stageAB(cur ^ 1, kt + 64);
#pragma unroll
    for (int kk = 0; kk < 2; ++kk) {
      bf16x8 a[2], bfr[4];
#pragma unroll
      for (int mi = 0; mi < 2; ++mi) {
        int ra = w * 32 + mi * 16 + li;
        a[mi] = *(const bf16x8*)&As[cur][ra][(kk * 32 + g * 8) ^ ((ra & 7) << 3)];
      }
#pragma unroll
      for (int ni = 0; ni < 4; ++ni) {
        int rb = ni * 16 + li;
        bfr[ni] = *(const bf16x8*)&Bs[cur][rb][(kk * 32 + g * 8) ^ ((rb & 7) << 3)];
      }
#pragma unroll
      for (int mi = 0; mi < 2; ++mi)
#pragma unroll
        for (int ni = 0; ni < 4; ++ni)
          acc[mi][ni] = mfma32(a[mi], bfr[ni], acc[mi][ni]);
    }
    __syncthreads();
    cur ^= 1;
  }
#pragma unroll
  for (int mi = 0; mi < 2; ++mi)
#pragma unroll
    for (int ni = 0; ni < 4; ++ni)
#pragma unroll
      for (int v = 0; v < 4; ++v) {
        int rr = m0 + w * 32 + mi * 16 + g * 4 + v;
        int cc = n0 + ni * 16 + li;
        float val = acc[mi][ni][v] + bias[cc];
        if (MODE == 1) {
          ((float*)Cv)[(size_t)rr * N + cc] = val;
        } else {
          // Qfrag[b][h][qt][c=n*2+kk][lane(gp,liq)][8]
          int b = rr >> 11, q = rr & 2047;
          int qt = q >> 5, n = (q >> 4) & 1, liq = q & 15;
          int h = (cc >> 6) & 15, kk2 = (cc >> 5) & 1, gp = (cc >> 3) & 3, j = cc & 7;
          size_t base = ((((size_t)b * HEADS + h) * 64 + qt) * 4 + n * 2 + kk2) * 512;
          ((u16*)Cv)[base + (size_t)(gp * 16 + liq) * 8 + j] = f2b(val);
        }
      }
}

// ---------------- attn_pv: 32 q-rows/wave; all-K=32 MFMA (QK + PV + denominator) ----------------
// db layout: [z*HEADS+h][q] = dinv = 1/denominator  (consumed by amean via FMA)
template<int MASKED>
static __device__ __forceinline__ void attn_pv_body(int z, int h, int qt, int w, int l,
                                                    const u16* __restrict__ Qfrag,
                                                    const u16* __restrict__ Kfrag,
                                                    const u16* __restrict__ Vfrag,
                                                    const unsigned* __restrict__ mbits,
                                                    u16* __restrict__ out01,
                                                    float* __restrict__ db,
                                                    u16* __restrict__ KV) {
  const int g = l >> 4, li = l & 15;
  const int b = z & 1;
  const u16* kfh = Kfrag + (size_t)(z * HEADS + h) * (32 * 8 * 512);
  const u16* vfh = Vfrag + (size_t)(z * HEADS + h) * (32 * 8 * 512);
  const u16* qfh = Qfrag + (((size_t)(b * HEADS + h) * 64 + qt) * 4) * 512;

  bf16x8 qf[2][2];
#pragma unroll
  for (int n = 0; n < 2; ++n)
#pragma unroll
    for (int kk = 0; kk < 2; ++kk)
      qf[n][kk] = *(const bf16x8*)&qfh[(n * 2 + kk) * 512 + l * 8];

  const unsigned* mrow0 = MASKED ? mbits + (size_t)(qt * 32 + li) * (LLL / 32) : nullptr;
  const unsigned* mrow1 = MASKED ? mrow0 + 16 * (LLL / 32) : nullptr;
  const int shb = 4 * g;
  bf16x8 ones8;
#pragma unroll
  for (int j = 0; j < 8; ++j) ones8[j] = __builtin_bit_cast(__bf16, (u16)0x3F80);

  auto stage = [&](int buf, int lt) {
    const u16* kfl = kfh + (size_t)lt * 4096;
    const u16* vfl = vfh + (size_t)lt * 4096;
#pragma unroll
    for (int i2 = 0; i2 < 2; ++i2) {
      int f = w * 2 + i2;
      const u16* gsrc = (f < 8 ? kfl + f * 512 : vfl + (f - 8) * 512) + l * 8;
      gload_lds16(gsrc, (char*)KV + buf * 16384 + f * 1024);
    }
  };

  f32x4 dacc[2] = {};     // denominator per n-half (matrix pipe, A = ones)
  f32x4 oacc[4][2] = {};  // [dt][n], unnormalized

  stage(0, 0);
  __syncthreads();
  int cur = 0;
  for (int lt = 0; lt < 32; ++lt) {
    if (lt + 1 < 32) stage(cur ^ 1, lt + 1);  // prefetch flies under compute
    unsigned mw[2][2];
    if (MASKED) {
      mw[0][0] = mrow0[lt * 2]; mw[0][1] = mrow0[lt * 2 + 1];
      mw[1][0] = mrow1[lt * 2]; mw[1][1] = mrow1[lt * 2 + 1];
    }
    const u16* Ks = KV + cur * 8192;
    const u16* Vs = Ks + 4096;

    auto qk = [&](f32x4 (&s)[2], int mt) {
      bf16x8 k0 = *(const bf16x8*)&Ks[(mt * 2 + 0) * 512 + l * 8];
      bf16x8 k1 = *(const bf16x8*)&Ks[(mt * 2 + 1) * 512 + l * 8];
      f32x4 zz = {};
      __builtin_amdgcn_s_setprio(1);
      s[0] = mfma32(k0, qf[0][0], zz);
      s[0] = mfma32(k1, qf[0][1], s[0]);
      s[1] = mfma32(k0, qf[1][0], zz);
      s[1] = mfma32(k1, qf[1][1], s[1]);
      __builtin_amdgcn_s_setprio(0);
    };
    auto sm = [&](f32x4 (&s)[2], int mt, s16x4 (&wpk)[2]) {
#pragma unroll
      for (int n = 0; n < 2; ++n) {
        unsigned mm = MASKED ? (mw[n][mt >> 1] >> ((mt & 1) * 16 + shb)) : 0u;
        f32x4 ev;
#pragma unroll
        for (int v = 0; v < 4; ++v) {
          float e = __builtin_amdgcn_exp2f(s[n][v]);    // K prescaled: zero prep
          if (MASKED) {
            int spread = ((int)(mm << (31 - v))) >> 31; // all-ones if keep
            e = __uint_as_float(__float_as_uint(e) & (unsigned)spread);
          }
          ev[v] = e;
        }
        bf16x4v wb = __builtin_convertvector(ev, bf16x4v);
        wpk[n] = __builtin_bit_cast(s16x4, wb);
      }
    };
    // PV + denominator for an mt pair, K=32 (permuted-k V layout)
    auto pv_pair = [&](s16x4 (&w0)[2], s16x4 (&w1)[2], int pair) {
      bf16x8 w8[2];
#pragma unroll
      for (int n = 0; n < 2; ++n) {
        bf16x4v a0 = __builtin_bit_cast(bf16x4v, w0[n]);
        bf16x4v a1 = __builtin_bit_cast(bf16x4v, w1[n]);
        w8[n] = __builtin_shufflevector(a0, a1, 0, 1, 2, 3, 4, 5, 6, 7);
      }
      __builtin_amdgcn_s_setprio(1);
      dacc[0] = mfma32(ones8, w8[0], dacc[0]);
      dacc[1] = mfma32(ones8, w8[1], dacc[1]);
#pragma unroll
      for (int dt = 0; dt < 4; ++dt) {
        bf16x8 vf = *(const bf16x8*)&Vs[(pair * 4 + dt) * 512 + l * 8];
#pragma unroll
        for (int n = 0; n < 2; ++n)
          oacc[dt][n] = mfma32(vf, w8[n], oacc[dt][n]);
      }
      __builtin_amdgcn_s_setprio(0);
    };

    f32x4 sA[2], sB[2];
    s16x4 wA[2], wB[2];
    qk(sA, 0); qk(sB, 1);
    sm(sA, 0, wA);
    qk(sA, 2);            // next pair's first QK overlaps sm/PV of pair 0
    sm(sB, 1, wB);
    pv_pair(wA, wB, 0);
    qk(sB, 3);
    sm(sA, 2, wA);
    sm(sB, 3, wB);
    pv_pair(wA, wB, 1);
    __syncthreads();
    cur ^= 1;
  }
  float dinv[2];
  dinv[0] = 1.0f / dacc[0][0];
  dinv[1] = 1.0f / dacc[1][0];
  if (l < 16) {
    db[(size_t)(z * HEADS + h) * SS + qt * 32 + li]      = dinv[0];
    db[(size_t)(z * HEADS + h) * SS + qt * 32 + 16 + li] = dinv[1];
  }
  u16* ob = out01 + (size_t)z * SS * DIM;
#pragma unroll
  for (int dt = 0; dt < 4; ++dt)
#pragma unroll
    for (int n = 0; n < 2; ++n) {
      f32x4 o = oacc[dt][n] * dinv[n];
      ushort4 us;
      us.x = f2b(o[0]); us.y = f2b(o[1]); us.z = f2b(o[2]); us.w = f2b(o[3]);
      *(ushort4*)&ob[((size_t)(qt * 32 + n * 16 + li)) * DIM + h * HD + dt * 16 + 4 * g] = us;
    }
}

__global__ __launch_bounds__(512, 4) void attn_pv(const u16* __restrict__ Qfrag,
                                                  const u16* __restrict__ Kfrag,
                                                  const u16* __restrict__ Vfrag,
                                                  const unsigned* __restrict__ mbits,
                                                  u16* __restrict__ out01,
                                                  float* __restrict__ db) {
  __shared__ u16 KV[2][8192];  // 32 KB double-buffered K+V tile
  // z-balanced XCD map (512 blocks): each XCD gets zh spanning all z
  const int flat = blockIdx.x;
  const int xcd = flat & 7, i = flat >> 3;     // i in [0,64)
  const int k = i >> 3, qg = i & 7;            // k in [0,8)
  const int zh = xcd + 8 * k;                  // [0,64)
  const int z = zh >> 4, h = zh & 15;
  const int w = threadIdx.x >> 6, l = threadIdx.x & 63;
  const int qt = qg * 8 + w;                   // [0,64)
  if (z < 2) attn_pv_body<1>(z, h, qt, w, l, Qfrag, Kfrag, Vfrag, mbits, out01, db, &KV[0][0]);
  else       attn_pv_body<0>(z, h, qt, w, l, Qfrag, Kfrag, Vfrag, mbits, out01, db, &KV[0][0]);
}

// ---------------- amean: 32 q-rows/wave, LDS-staged K; mask hoisted out of the h-loop ----------------
// a[q][l] = mask(q,l) * (1/16) * sum_h exp2(s_h)*dinv_h  -- mask applied ONCE at the end.
template<int MASKED>
static __device__ __forceinline__ void amean_body(int z, int qt, int lt, int w, int l,
                                                  const u16* __restrict__ Qfrag,
                                                  const u16* __restrict__ Kfrag,
                                                  const unsigned* __restrict__ mbits,
                                                  const float* __restrict__ db,
                                                  float* __restrict__ aout,
                                                  u16* __restrict__ KS) {
  const int g = l >> 4, li = l & 15;
  const int b = z & 1;

  const u16* qf_base = Qfrag + (((size_t)(b * HEADS) * 64 + qt) * 4) * 512 + l * 8;
  const float* dbb = db + (size_t)(z * HEADS) * SS + qt * 32 + li;

  auto stageK = [&](int buf, int h) {
    const u16* kfh = Kfrag + ((((size_t)(z * HEADS + h)) * 32 + lt) * 8) * 512;
#pragma unroll
    for (int i2 = 0; i2 < 2; ++i2) {
      int f = w * 2 + i2;
      gload_lds16(kfh + f * 512 + l * 8, (char*)KS + buf * 8192 + f * 1024);
    }
  };

  f32x4 asum[4][2] = {};
  stageK(0, 0);
  __syncthreads();
#pragma unroll 2
  for (int h = 0; h < HEADS; ++h) {
    if (h + 1 < HEADS) stageK((h + 1) & 1, h + 1);   // prefetch under compute
    float dv[2];
    dv[0] = dbb[(size_t)h * SS];                     // dinv, precomputed (mask-correct)
    dv[1] = dbb[(size_t)h * SS + 16];
    bf16x8 qf[2][2];
#pragma unroll
    for (int n = 0; n < 2; ++n)
#pragma unroll
      for (int kk = 0; kk < 2; ++kk)
        qf[n][kk] = *(const bf16x8*)&qf_base[(size_t)h * (64 * 4 * 512) + (n * 2 + kk) * 512];
    const u16* Ks = KS + (h & 1) * 4096;
#pragma unroll
    for (int mt = 0; mt < 4; ++mt) {
      bf16x8 k0 = *(const bf16x8*)&Ks[(mt * 2 + 0) * 512 + l * 8];
      bf16x8 k1 = *(const bf16x8*)&Ks[(mt * 2 + 1) * 512 + l * 8];
#pragma unroll
      for (int n = 0; n < 2; ++n) {
        f32x4 s = {};
        s = mfma32(k0, qf[n][0], s);
        s = mfma32(k1, qf[n][1], s);
#pragma unroll
        for (int v = 0; v < 4; ++v)
          asum[mt][n][v] = __builtin_fmaf(__builtin_amdgcn_exp2f(s[v]), dv[n], asum[mt][n][v]);
      }
    }
    __syncthreads();  // waves done reading Ks[h&1]; h+1 loads drained
  }
  // final mask (once per output element) + scale + store
  float* ab = aout + (size_t)z * SS * LLL;
#pragma unroll
  for (int mt = 0; mt < 4; ++mt)
#pragma unroll
    for (int n = 0; n < 2; ++n) {
      f32x4 o = asum[mt][n] * 0.0625f;
      if (MASKED) {
        const unsigned* mrow = mbits + (size_t)(qt * 32 + n * 16 + li) * (LLL / 32) + lt * 2;
        unsigned mm = mrow[mt >> 1] >> ((mt & 1) * 16 + 4 * g);
#pragma unroll
        for (int v = 0; v < 4; ++v) {
          int spread = ((int)(mm << (31 - v))) >> 31;  // all-ones if keep
          o[v] = __uint_as_float(__float_as_uint(o[v]) & (unsigned)spread);
        }
      }
      f32x4* dst = (f32x4*)&ab[(size_t)(qt * 32 + n * 16 + li) * LLL + lt * 64 + mt * 16 + 4 * g];
      __builtin_nontemporal_store(o, dst);
    }
}

__global__ __launch_bounds__(256, 4) void amean(const u16* __restrict__ Qfrag,
                                                const u16* __restrict__ Kfrag,
                                                const unsigned* __restrict__ mbits,
                                                const float* __restrict__ db,
                                                float* __restrict__ aout) {
  __shared__ u16 KS[2][4096];  // 16 KB double-buffered K tile
  // z-balanced XCD map over (z,lt) groups (2048 blocks)
  const int flat = blockIdx.x;
  const int xcd = flat & 7, i = flat >> 3;     // i in [0,256)
  const int k = i >> 4, qg = i & 15;           // k in [0,16)
  const int zlt = xcd + 8 * k;                 // [0,128)
  const int z = zlt >> 5, lt = zlt & 31;
  const int w = threadIdx.x >> 6, l = threadIdx.x & 63;
  const int qt = qg * 4 + w;                   // [0,64)
  if (z < 2) amean_body<1>(z, qt, lt, w, l, Qfrag, Kfrag, mbits, db, aout, &KS[0][0]);
  else       amean_body<0>(z, qt, lt, w, l, Qfrag, Kfrag, mbits, db, aout, &KS[0][0]);
}

// ---------------- gated merge ----------------
__global__ void merge_kernel(const u16* __restrict__ o01,
                             const float* __restrict__ gate,
                             u16* __restrict__ merged) {
  int i = blockIdx.x * blockDim.x + threadIdx.x;
  float gv = gate[0];
  float g = 1.0f / (1.0f + __builtin_amdgcn_exp2f(-gv * LOG2E));
  const size_t n = (size_t)BB * SS * DIM;
  ushort4 a = ((const ushort4*)o01)[i];
  ushort4 c = ((const ushort4*)(o01 + n))[i];
  ushort4 o;
  o.x = f2b(g * b2f(a.x) + (1.f - g) * b2f(c.x));
  o.y = f2b(g * b2f(a.y) + (1.f - g) * b2f(c.y));
  o.z = f2b(g * b2f(a.z) + (1.f - g) * b2f(c.z));
  o.w = f2b(g * b2f(a.w) + (1.f - g) * b2f(c.w));
  ((ushort4*)merged)[i] = o;
}

extern "C" void kernel_launch(void* const* d_in, const int* in_sizes, int n_in,
                              void* d_out, int out_size, void* d_ws, size_t ws_size,
                              hipStream_t stream) {
  const float* query = (const float*)d_in[0];
  const float* k0f   = (const float*)d_in[1];
  const float* v0f   = (const float*)d_in[2];
  const float* k1f   = (const float*)d_in[3];
  const float* v1f   = (const float*)d_in[4];
  const int*   mask  = (const int*)d_in[5];
  const float* Wqf   = (const float*)d_in[6];
  const float* bq    = (const float*)d_in[7];
  const float* Wof   = (const float*)d_in[8];
  const float* bo    = (const float*)d_in[9];
  const float* gate  = (const float*)d_in[10];
  float* out = (float*)d_out;

  const size_t nQ = (size_t)BB * SS * DIM;
  const size_t nW = (size_t)DIM * DIM;

  char* ws = (char*)d_ws;
  size_t off = 0;
  auto alloc = [&](size_t bytes) -> char* {
    char* p = ws + off;
    off += (bytes + 255) & ~(size_t)255;
    return p;
  };
  u16*      queryb  = (u16*)alloc(nQ * 2);             // reused as mergedb later
  u16*      wqb     = (u16*)alloc(nW * 2);
  u16*      wob     = (u16*)alloc(nW * 2);
  u16*      Qfrag   = (u16*)alloc(nQ * 2);             // [b][h][qt][c][lane][8]
  u16*      Kfrag   = (u16*)alloc((size_t)2 * nQ * 2); // [z][h][lt][c][lane][8] (prescaled)
  u16*      Vfrag   = (u16*)alloc((size_t)2 * nQ * 2); // K=32-PV layout
  unsigned* mbits   = (unsigned*)alloc((size_t)SS * (LLL / 32) * 4);
  float*    db      = (float*)alloc((size_t)4 * HEADS * SS * 4);  // dinv per [z][h][q]
  u16*      out01   = (u16*)alloc((size_t)2 * nQ * 2);
  u16*      mergedb = queryb;  // queryb dead after q-proj gemm

  {
    int na4 = (int)(nQ / 4), nb4 = (int)(nW / 4);
    int ncvt = na4 + 2 * nb4;
    int nmask = SS * (LLL / 32);
    prep<<<dim3((ncvt + nmask) / 256), dim3(256), 0, stream>>>(
        query, Wqf, Wof, queryb, wqb, wob, mask, mbits, na4, nb4, ncvt);
  }

  pack_k<<<dim3(LLL / 64 / 4, HEADS, 4), dim3(256), 0, stream>>>(k0f, k1f, Kfrag);
  pack_v<<<dim3(LLL / 64, HEADS, 4), dim3(256), 0, stream>>>(v0f, v1f, Vfrag);

  // q projection straight into fragment layout (128x64 tiles, XCD-chunked 1-D grid)
  gemm_nt<2><<<dim3(512), dim3(256), 0, stream>>>(
      queryb, wqb, bq, (void*)Qfrag, BB * SS, DIM, DIM);

  // fused single-pass attention: 32 rows/wave, all-K=32 MFMA, double-buffered LDS staging
  attn_pv<<<dim3(512), dim3(512), 0, stream>>>(Qfrag, Kfrag, Vfrag, mbits, out01, db);

  // head-mean attention maps straight into d_out (4-wave shared K tiles, mask hoisted)
  amean<<<dim3(2048), dim3(256), 0, stream>>>(Qfrag, Kfrag, mbits, db, out + nQ);

  merge_kernel<<<dim3((int)(nQ / 4 / 256)), dim3(256), 0, stream>>>(out01, gate, mergedb);

  gemm_nt<1><<<dim3(512), dim3(256), 0, stream>>>(
      mergedb, wob, bo, (void*)out, BB * SS, DIM, DIM);
}